// Round 15
// baseline (1981.406 us; speedup 1.0000x reference)
//
#include <hip/hip_runtime.h>
#include <math.h>

#define T_DIM 1024
#define B_DIM 256
#define D_DIM 32
#define H_DIM 128

// Bit-faithful XLA-CPU / Eigen fast-tanh, WITH-FMA variant
// (xla/service/llvm_ir/math_ops.cc EmitFastTanh(with_fma=true), identical to
// Eigen generic_fast_tanh_float under EIGEN_VECTORIZE_FMA):
//   clamp to +-7.99881172180175781f  (FMA-variant constant!)
//   p = fma(x2, a13, a11); p = fma(x2, p, a9); ... ; p = fma(x2, p, a1)
//   num = xc * p
//   q = fma(x2, b6, b4); q = fma(x2, q, b2); q = fma(x2, q, b0)
//   r = num / q;  result = |x| < 0.0004 ? x : r
// Round-14 used the NON-FMA variant (clamp 7.905311, separate mul/add) and
// scored 26 (first discordant flip t~1011): the residual channel is exactly
// the (7.905, 7.9988) band + FMA-vs-separate ulps. This is that fix.
__device__ __forceinline__ float xla_tanh_fma_f32(float x) {
  const float plim = 7.99881172180175781f;
  float xc = fminf(fmaxf(x, -plim), plim);
  float x2 = __fmul_rn(xc, xc);
  float p;
  p = fmaf(x2, -2.76076847742355e-16f, 2.00018790482477e-13f);
  p = fmaf(x2, p, -8.60467152213735e-11f);
  p = fmaf(x2, p,  5.12229709037114e-08f);
  p = fmaf(x2, p,  1.48572235717979e-05f);
  p = fmaf(x2, p,  6.37261928875436e-04f);
  p = fmaf(x2, p,  4.89352455891786e-03f);
  float num = __fmul_rn(xc, p);
  float q;
  q = fmaf(x2, 1.19825839466702e-06f, 1.18534705686654e-04f);
  q = fmaf(x2, q, 2.26843463243900e-03f);
  q = fmaf(x2, q, 4.89352518554385e-03f);
  float r = __fdiv_rn(num, q);
  return (fabsf(x) < 0.0004f) ? x : r;
}

// One block per batch row, 128 threads, lane j owns output j.
// Target: BIT-EXACT replication of the recomputed reference = jax/XLA-CPU
// f32 trajectory:
//   dots: Eigen/oneDNN gemm -> per-element serial ascending-k f32 FMA chain,
//         single accumulator from 0 (beta=0)
//   fusion: a = (d1 + d2) + b   (f32, left-assoc)
//   tanh: EmitFastTanh with_fma (above)
//   h' = h + th in f32; state carried f32.
__global__ __launch_bounds__(128, 1) void diffeq_kernel(
    const float* __restrict__ x, const float* __restrict__ state,
    const float* __restrict__ W_in, const float* __restrict__ W_h,
    const float* __restrict__ bias, float* __restrict__ out) {
  extern __shared__ float lds[];
  float* x_lds = lds;                    // T*D = 32768 floats (128 KiB)
  float* h0 = lds + T_DIM * D_DIM;       // 128 floats
  float* h1 = h0 + H_DIM;                // 128 floats

  const int b = blockIdx.x;
  const int j = threadIdx.x;             // output index 0..127

  // ---- stage x[:, b, :] into LDS (float4, coalesced) ----
  {
    const float4* xg = reinterpret_cast<const float4*>(x + (size_t)b * D_DIM);
    float4* xl = reinterpret_cast<float4*>(x_lds);
    const int stride4 = B_DIM * D_DIM / 4;  // 2048 float4 per t
    for (int i = j; i < T_DIM * D_DIM / 4; i += 128) {
      int t  = i >> 3;
      int d4 = i & 7;
      xl[i] = xg[(size_t)t * stride4 + d4];
    }
  }
  h0[j] = state[(size_t)b * H_DIM + j];

  // ---- this lane's full weight columns, f32 in registers ----
  float wx[D_DIM];
  float wh[H_DIM];
#pragma unroll
  for (int i = 0; i < D_DIM; ++i) wx[i] = W_in[i * H_DIM + j];
#pragma unroll
  for (int i = 0; i < H_DIM; ++i) wh[i] = W_h[i * H_DIM + j];
  const float bj = bias[j];
  __syncthreads();

  float* hc = h0;
  float* hn = h1;
  const size_t out_row = (size_t)b * H_DIM + j;

  for (int t = 0; t < T_DIM; ++t) {
    const float* xrow = x_lds + t * D_DIM;

    // gemm semantics: serial ascending-k fused-FMA chain, single acc.
    float s1 = 0.f;
#pragma unroll
    for (int k = 0; k < D_DIM; ++k) s1 = fmaf(xrow[k], wx[k], s1);
    float s2 = 0.f;
#pragma unroll
    for (int k = 0; k < H_DIM; ++k) s2 = fmaf(hc[k], wh[k], s2);

    float a  = __fadd_rn(__fadd_rn(s1, s2), bj);  // XLA fusion: (d1+d2)+b
    float th = xla_tanh_fma_f32(a);               // FMA-variant fast tanh
    float hv = __fadd_rn(hc[j], th);              // f32 state update

    hn[j] = hv;
    __syncthreads();
    // Store AFTER the barrier: vmcnt drain overlaps next step's compute.
    out[(size_t)t * (B_DIM * H_DIM) + out_row] = hv;

    float* tmp = hc; hc = hn; hn = tmp;
  }

  // final_state = h after last step (== outputs[T-1])
  out[(size_t)T_DIM * B_DIM * H_DIM + out_row] = hc[j];
}

extern "C" void kernel_launch(void* const* d_in, const int* in_sizes, int n_in,
                              void* d_out, int out_size, void* d_ws, size_t ws_size,
                              hipStream_t stream) {
  const float* x     = (const float*)d_in[0];
  const float* state = (const float*)d_in[1];
  const float* W_in  = (const float*)d_in[2];
  const float* W_h   = (const float*)d_in[3];
  const float* bias  = (const float*)d_in[4];
  float* out = (float*)d_out;

  const size_t smem = (size_t)(T_DIM * D_DIM + 2 * H_DIM) * sizeof(float);  // 129 KiB
  static bool attr_set = false;
  if (!attr_set) {
    (void)hipFuncSetAttribute((const void*)diffeq_kernel,
                              hipFuncAttributeMaxDynamicSharedMemorySize,
                              (int)smem);
    attr_set = true;
  }
  diffeq_kernel<<<B_DIM, 128, smem, stream>>>(x, state, W_in, W_h, bias, out);
}

// Round 16
// 1592.655 us; speedup vs baseline: 1.2441x; 1.2441x over previous
//
#include <hip/hip_runtime.h>
#include <math.h>

#define T_DIM 1024
#define B_DIM 256
#define D_DIM 32
#define H_DIM 128

// Bit-faithful XLA-CPU / Eigen fast-tanh, WITH-FMA variant — FROZEN.
// (clamp +-7.99881172180175781f, fmaf-Horner, |x|<0.0004 passthrough.)
// Verified bit-exact vs the harness reference in round 15 (absmax 0.0).
__device__ __forceinline__ float xla_tanh_fma_f32(float x) {
  const float plim = 7.99881172180175781f;
  float xc = fminf(fmaxf(x, -plim), plim);
  float x2 = __fmul_rn(xc, xc);
  float p;
  p = fmaf(x2, -2.76076847742355e-16f, 2.00018790482477e-13f);
  p = fmaf(x2, p, -8.60467152213735e-11f);
  p = fmaf(x2, p,  5.12229709037114e-08f);
  p = fmaf(x2, p,  1.48572235717979e-05f);
  p = fmaf(x2, p,  6.37261928875436e-04f);
  p = fmaf(x2, p,  4.89352455891786e-03f);
  float num = __fmul_rn(xc, p);
  float q;
  q = fmaf(x2, 1.19825839466702e-06f, 1.18534705686654e-04f);
  q = fmaf(x2, q, 2.26843463243900e-03f);
  q = fmaf(x2, q, 4.89352518554385e-03f);
  float r = __fdiv_rn(num, q);
  return (fabsf(x) < 0.0004f) ? x : r;
}

// One step of the recurrence for lane j. ARITHMETIC IS FROZEN (bit-exact):
// serial ascending-k fmaf chains, (s1+s2)+b, fast-tanh, f32 state add.
// Only memory residency is optimized: W_h column-quads in LDS (bandwidth-
// ideal b128 reads), h as b128 broadcasts, x from prefetched registers.
__device__ __forceinline__ float diffeq_step(
    const float4* __restrict__ whq, const float4* __restrict__ hq,
    const float* __restrict__ hcur_p, const float4 xb[8],
    const float wx[D_DIM], float bj, int j) {
  float s1 = 0.f;
#pragma unroll
  for (int i = 0; i < 8; ++i) {
    s1 = fmaf(xb[i].x, wx[4 * i + 0], s1);
    s1 = fmaf(xb[i].y, wx[4 * i + 1], s1);
    s1 = fmaf(xb[i].z, wx[4 * i + 2], s1);
    s1 = fmaf(xb[i].w, wx[4 * i + 3], s1);
  }
  float s2 = 0.f;
#pragma unroll
  for (int q = 0; q < 32; ++q) {
    float4 h4 = hq[q];                 // broadcast read (same addr all lanes)
    float4 w4 = whq[q * H_DIM + j];    // column quad: even-bank, 8cyc ideal
    s2 = fmaf(h4.x, w4.x, s2);
    s2 = fmaf(h4.y, w4.y, s2);
    s2 = fmaf(h4.z, w4.z, s2);
    s2 = fmaf(h4.w, w4.w, s2);
  }
  float a  = __fadd_rn(__fadd_rn(s1, s2), bj);
  float th = xla_tanh_fma_f32(a);
  return __fadd_rn(*hcur_p, th);
}

__global__ __launch_bounds__(128, 1) void diffeq_kernel(
    const float* __restrict__ x, const float* __restrict__ state,
    const float* __restrict__ W_in, const float* __restrict__ W_h,
    const float* __restrict__ bias, float* __restrict__ out) {
  extern __shared__ float4 smem4[];
  float4* whq = smem4;                         // [32*128] quads = 64 KiB
  float*  h0  = (float*)(smem4 + 32 * H_DIM);  // 128 floats
  float*  h1  = h0 + H_DIM;                    // 128 floats

  const int b   = blockIdx.x;
  const int tid = threadIdx.x;
  const int j   = tid;                         // output index 0..127

  // ---- stage W_h into LDS as column quads: whq[(k/4)*128 + j].[k%4] ----
  for (int idx = tid; idx < H_DIM * H_DIM; idx += 128) {
    int k  = idx >> 7;
    int jj = idx & 127;
    reinterpret_cast<float*>(&whq[(k >> 2) * H_DIM + jj])[k & 3] = W_h[idx];
  }
  h0[j] = state[(size_t)b * H_DIM + j];

  // ---- this lane's W_in column (32 VGPRs) ----
  float wx[D_DIM];
#pragma unroll
  for (int k = 0; k < D_DIM; ++k) wx[k] = W_in[k * H_DIM + j];
  const float bj = bias[j];
  __syncthreads();

  const size_t out_row = (size_t)b * H_DIM + j;
  const float4* xg = reinterpret_cast<const float4*>(x + (size_t)b * D_DIM);
  const int xstride4 = B_DIM * D_DIM / 4;      // 2048 float4 per t

  // Prefetch x row t=0 into registers (all lanes same addrs; L3-resident).
  float4 xbA[8], xbB[8];
#pragma unroll
  for (int i = 0; i < 8; ++i) xbA[i] = xg[i];

  float lasthv = 0.f;
  // t-loop unrolled by 2 for static x/h ping-pong (no dynamic reg indexing).
  for (int t = 0; t < T_DIM; t += 2) {
    // ---- even step: h0 -> h1, consumes xbA, prefetches xbB (t+1) ----
#pragma unroll
    for (int i = 0; i < 8; ++i) xbB[i] = xg[(size_t)(t + 1) * xstride4 + i];
    {
      float hv = diffeq_step(whq, reinterpret_cast<const float4*>(h0),
                             h0 + j, xbA, wx, bj, j);
      h1[j] = hv;
      __syncthreads();
      out[(size_t)t * (B_DIM * H_DIM) + out_row] = hv;
    }
    // ---- odd step: h1 -> h0, consumes xbB, prefetches xbA (t+2) ----
    if (t + 2 < T_DIM) {
#pragma unroll
      for (int i = 0; i < 8; ++i) xbA[i] = xg[(size_t)(t + 2) * xstride4 + i];
    }
    {
      float hv = diffeq_step(whq, reinterpret_cast<const float4*>(h1),
                             h1 + j, xbB, wx, bj, j);
      h0[j] = hv;
      __syncthreads();
      out[(size_t)(t + 1) * (B_DIM * H_DIM) + out_row] = hv;
      lasthv = hv;
    }
  }

  // final_state = h after last step (== outputs[T-1])
  out[(size_t)T_DIM * B_DIM * H_DIM + out_row] = lasthv;
}

extern "C" void kernel_launch(void* const* d_in, const int* in_sizes, int n_in,
                              void* d_out, int out_size, void* d_ws, size_t ws_size,
                              hipStream_t stream) {
  const float* x     = (const float*)d_in[0];
  const float* state = (const float*)d_in[1];
  const float* W_in  = (const float*)d_in[2];
  const float* W_h   = (const float*)d_in[3];
  const float* bias  = (const float*)d_in[4];
  float* out = (float*)d_out;

  const size_t smem = (size_t)(32 * H_DIM) * sizeof(float4)
                    + (size_t)(2 * H_DIM) * sizeof(float);   // 65 KiB
  static bool attr_set = false;
  if (!attr_set) {
    (void)hipFuncSetAttribute((const void*)diffeq_kernel,
                              hipFuncAttributeMaxDynamicSharedMemorySize,
                              (int)smem);
    attr_set = true;
  }
  diffeq_kernel<<<B_DIM, 128, smem, stream>>>(x, state, W_in, W_h, bias, out);
}

// Round 17
// 990.396 us; speedup vs baseline: 2.0006x; 1.6081x over previous
//
#include <hip/hip_runtime.h>
#include <math.h>

#define T_DIM 1024
#define B_DIM 256
#define D_DIM 32
#define H_DIM 128

// Bit-faithful XLA-CPU / Eigen fast-tanh, WITH-FMA variant — FROZEN.
// Verified bit-exact vs the harness reference in round 15 (absmax 0.0).
__device__ __forceinline__ float xla_tanh_fma_f32(float x) {
  const float plim = 7.99881172180175781f;
  float xc = fminf(fmaxf(x, -plim), plim);
  float x2 = __fmul_rn(xc, xc);
  float p;
  p = fmaf(x2, -2.76076847742355e-16f, 2.00018790482477e-13f);
  p = fmaf(x2, p, -8.60467152213735e-11f);
  p = fmaf(x2, p,  5.12229709037114e-08f);
  p = fmaf(x2, p,  1.48572235717979e-05f);
  p = fmaf(x2, p,  6.37261928875436e-04f);
  p = fmaf(x2, p,  4.89352455891786e-03f);
  float num = __fmul_rn(xc, p);
  float q;
  q = fmaf(x2, 1.19825839466702e-06f, 1.18534705686654e-04f);
  q = fmaf(x2, q, 2.26843463243900e-03f);
  q = fmaf(x2, q, 4.89352518554385e-03f);
  float r = __fdiv_rn(num, q);
  return (fabsf(x) < 0.0004f) ? x : r;
}

// One recurrence step for lane j. ARITHMETIC FROZEN (bit-exact):
// serial ascending-k fmaf chains, (s1+s2)+b, fast-tanh, f32 state add.
// Memory: W_h column in 128 VGPRs (wh), h via conflict-free BROADCAST
// float4 LDS reads, x from prefetched registers.
__device__ __forceinline__ float diffeq_step(
    const float4* __restrict__ hq, const float* __restrict__ hsc,
    const float4 xb[8], const float wx[D_DIM], const float wh[H_DIM],
    float bj, int j) {
  float s1 = 0.f;
#pragma unroll
  for (int i = 0; i < 8; ++i) {
    s1 = fmaf(xb[i].x, wx[4 * i + 0], s1);
    s1 = fmaf(xb[i].y, wx[4 * i + 1], s1);
    s1 = fmaf(xb[i].z, wx[4 * i + 2], s1);
    s1 = fmaf(xb[i].w, wx[4 * i + 3], s1);
  }
  float s2 = 0.f;
#pragma unroll
  for (int q = 0; q < 32; ++q) {
    float4 h4 = hq[q];               // broadcast read: all lanes same addr
    s2 = fmaf(h4.x, wh[4 * q + 0], s2);
    s2 = fmaf(h4.y, wh[4 * q + 1], s2);
    s2 = fmaf(h4.z, wh[4 * q + 2], s2);
    s2 = fmaf(h4.w, wh[4 * q + 3], s2);
  }
  float a  = __fadd_rn(__fadd_rn(s1, s2), bj);
  float th = xla_tanh_fma_f32(a);
  return __fadd_rn(hsc[j], th);      // own h: scalar conflict-free read
}

__global__ __launch_bounds__(128, 1) void diffeq_kernel(
    const float* __restrict__ x, const float* __restrict__ state,
    const float* __restrict__ W_in, const float* __restrict__ W_h,
    const float* __restrict__ bias, float* __restrict__ out) {
  __shared__ __align__(16) float h0[H_DIM];
  __shared__ __align__(16) float h1[H_DIM];

  const int b = blockIdx.x;
  const int j = threadIdx.x;                   // output index 0..127

  // ---- this lane's weight columns into REGISTERS ----
  float wh[H_DIM];                             // 128 VGPRs; loads coalesced
#pragma unroll
  for (int k = 0; k < H_DIM; ++k) wh[k] = W_h[k * H_DIM + j];
  float wx[D_DIM];
#pragma unroll
  for (int k = 0; k < D_DIM; ++k) wx[k] = W_in[k * H_DIM + j];
  const float bj = bias[j];

  h0[j] = state[(size_t)b * H_DIM + j];
  __syncthreads();

  const size_t out_row = (size_t)b * H_DIM + j;
  const float4* xg = reinterpret_cast<const float4*>(x + (size_t)b * D_DIM);
  const int xstride4 = B_DIM * D_DIM / 4;      // 2048 float4 per t

  // Prefetch x row t=0 (all lanes same addrs; L2/L3-resident).
  float4 xbA[8], xbB[8];
#pragma unroll
  for (int i = 0; i < 8; ++i) xbA[i] = xg[i];

  float lasthv = 0.f;
  // t-loop unrolled by 2: static h ping-pong + x double-buffer.
  for (int t = 0; t < T_DIM; t += 2) {
    // ---- even step: h0 -> h1, consumes xbA, prefetches xbB (t+1) ----
#pragma unroll
    for (int i = 0; i < 8; ++i) xbB[i] = xg[(size_t)(t + 1) * xstride4 + i];
    {
      float hv = diffeq_step(reinterpret_cast<const float4*>(h0), h0,
                             xbA, wx, wh, bj, j);
      h1[j] = hv;
      __syncthreads();
      // store AFTER barrier: vmcnt drain lands at next barrier, hidden.
      out[(size_t)t * (B_DIM * H_DIM) + out_row] = hv;
    }
    // ---- odd step: h1 -> h0, consumes xbB, prefetches xbA (t+2) ----
    if (t + 2 < T_DIM) {
#pragma unroll
      for (int i = 0; i < 8; ++i) xbA[i] = xg[(size_t)(t + 2) * xstride4 + i];
    }
    {
      float hv = diffeq_step(reinterpret_cast<const float4*>(h1), h1,
                             xbB, wx, wh, bj, j);
      h0[j] = hv;
      __syncthreads();
      out[(size_t)(t + 1) * (B_DIM * H_DIM) + out_row] = hv;
      lasthv = hv;
    }
  }

  // final_state = h after last step (== outputs[T-1])
  out[(size_t)T_DIM * B_DIM * H_DIM + out_row] = lasthv;
}

extern "C" void kernel_launch(void* const* d_in, const int* in_sizes, int n_in,
                              void* d_out, int out_size, void* d_ws, size_t ws_size,
                              hipStream_t stream) {
  const float* x     = (const float*)d_in[0];
  const float* state = (const float*)d_in[1];
  const float* W_in  = (const float*)d_in[2];
  const float* W_h   = (const float*)d_in[3];
  const float* bias  = (const float*)d_in[4];
  float* out = (float*)d_out;

  diffeq_kernel<<<B_DIM, 128, 0, stream>>>(x, state, W_in, W_h, bias, out);
}